// Round 8
// baseline (200.377 us; speedup 1.0000x reference)
//
#include <hip/hip_runtime.h>

#define BTOT 16384

typedef __attribute__((ext_vector_type(8))) short bf16x8;   // 8 bf16 in 4 VGPRs
typedef __attribute__((ext_vector_type(4))) float f32x4;

#define MFMA16(a,b,c) __builtin_amdgcn_mfma_f32_16x16x32_bf16((a),(b),(c),0,0,0)

// ---- bf16 conversion helpers: HW packed cvt if available, manual RNE else ----
#if __has_builtin(__builtin_amdgcn_cvt_pk_bf16_f32)
typedef __attribute__((ext_vector_type(2))) __bf16 hwbf2;
static __device__ __forceinline__ unsigned pk2(float a, float b) {
    hwbf2 v = __builtin_amdgcn_cvt_pk_bf16_f32(a, b);
    return __builtin_bit_cast(unsigned, v);
}
#else
static __device__ __forceinline__ unsigned pk2(float a, float b) {
    unsigned ua = __float_as_uint(a), ub = __float_as_uint(b);
    unsigned ra = (ua + 0x7FFFu + ((ua >> 16) & 1u)) >> 16;
    unsigned rb = (ub + 0x7FFFu + ((ub >> 16) & 1u)) >> 16;
    return (ra & 0xFFFFu) | (rb << 16);
}
#endif
static __device__ __forceinline__ unsigned short bfhi(float x) {
    return (unsigned short)(pk2(x, 0.f) & 0xFFFFu);
}
static __device__ __forceinline__ float b2f(unsigned short h) {
    return __uint_as_float(((unsigned)h) << 16);
}
static __device__ __forceinline__ float lof(float x) { return x - b2f(bfhi(x)); }
static __device__ __forceinline__ short f2s(float x) { return (short)bfhi(x); }
// manual RNE for the pack kernel (identical rounding either path)
static __device__ __forceinline__ unsigned short bfhi_m(float x) {
    unsigned u = __float_as_uint(x);
    return (unsigned short)((u + 0x7FFFu + ((u >> 16) & 1u)) >> 16);
}
static __device__ __forceinline__ unsigned short bflo_m(float x) {
    unsigned short h = bfhi_m(x);
    return bfhi_m(x - b2f(h));
}
static __device__ __forceinline__ bf16x8 zero8() {
    bf16x8 v;
    #pragma unroll
    for (int i = 0; i < 8; ++i) v[i] = 0;
    return v;
}
static __device__ __forceinline__ bf16x8 mk8(unsigned a, unsigned b, unsigned c, unsigned d) {
    union { unsigned u[4]; bf16x8 v; } x;
    x.u[0] = a; x.u[1] = b; x.u[2] = c; x.u[3] = d;
    return x.v;
}

// ---------------------------------------------------------------------------
// Workspace (shorts). Frags are 512 shorts each, frag f at pk[f*512 + lane*8 + j].
// K-slot permutation kappa(q,j) = (j<4 ? 4q+j : 16+4q+(j-4)) matches the
// register layout of MFMA D-tiles (hi pair P0=r0r1, P1=r2r3 per sub-tile).
// f 0..3  A1     : Wh1^T A-frags (k=0..6 feats, k=7 bias, else 0)
// f 4..7  A_Wh2T : f=4+fo*2+kf; A[m=fo*16+c][hid=kf*32+kappa(q,j)] = wh_w2[hid][m]
// f 8..9  A_W1eT : f=8+ot;      A[m=ot*16+c][feat=kappa(q,j)]      = W1eff[feat][m]
// f 10..21 BrL2(split K=192) | 22..45 Bg1(split) | 46..57 Bg2(split)
// f 58..67 Bv1 | 68..102 Bv2.
// shorts 52736..52864: bg1 f32[64]; 52864..52928: bg2 f32[32];
// 53248..+524288: r2 bf16. Total ~1.16 MB.
// ---------------------------------------------------------------------------
__global__ void pack_frags(
    const float* __restrict__ wh_w1, const float* __restrict__ wh_b1,
    const float* __restrict__ wh_w2,
    const float* __restrict__ root_rh1, const float* __restrict__ root_hh1,
    const float* __restrict__ rel_hh1,
    const float* __restrict__ wr_w2,
    const float* __restrict__ rel_hr1, const float* __restrict__ root_hr1,
    const float* __restrict__ rel_rh1,
    const float* __restrict__ rel_hr2, const float* __restrict__ root_hr2,
    const float* __restrict__ vn_w1, const float* __restrict__ vn_w2,
    const float* __restrict__ brel_hr1, const float* __restrict__ brel_rh1,
    const float* __restrict__ brel_hh1, const float* __restrict__ brel_hr2,
    short* __restrict__ pk)
{
    int t = blockIdx.x * blockDim.x + threadIdx.x;
    if (t < 52736) {
        int f = t >> 9, r = t & 511;
        int lane = r >> 3, j = r & 7;
        int q = lane >> 4, c = lane & 15;
        int k = q * 8 + j;
        int kap = (j < 4) ? (4 * q + j) : (16 + 4 * q + (j - 4));
        unsigned short outv;
        if (f < 4) {                                   // A1: Wh1^T (+bias row k=7)
            int m = f * 16 + c;
            float v = (k < 7) ? wh_w1[k * 64 + m] : (k == 7 ? wh_b1[m] : 0.f);
            outv = bfhi_m(v);
        } else if (f < 8) {                            // A_Wh2T, kappa K-order
            int u = f - 4, fo = u >> 1, kf = u & 1;
            int m = fo * 16 + c;
            int hid = kf * 32 + kap;
            outv = bfhi_m(wh_w2[hid * 32 + m]);
        } else if (f < 10) {                           // A_W1effT, kappa K-order
            int ot = f - 8;
            int m = ot * 16 + c;
            outv = bfhi_m(root_rh1[kap * 32 + m] + root_hh1[kap * 32 + m] - rel_hh1[kap * 32 + m]);
        } else if (f < 22) {                           // BrL2 split
            int u = f - 10, ks = u >> 1, nt = u & 1;
            int kp = ks * 32 + k;                      // 0..191
            float w = wr_w2[(kp & 63) * 32 + nt * 16 + c];
            outv = (kp < 128) ? bfhi_m(w) : bflo_m(w);
        } else if (f < 46) {                           // Bg1 split
            int u = f - 22, ks = u >> 2, nt = u & 3;
            int kp = ks * 32 + k, seg = kp >> 5, kk = kp & 31;
            int n2 = (nt & 1) * 16 + c;
            bool sPart = (seg < 2) || (seg == 4);
            const float* W = (nt < 2) ? (sPart ? rel_hr1 : root_hr1)
                                      : (sPart ? rel_hh1 : rel_rh1);
            float w = W[kk * 32 + n2];
            outv = (seg < 4) ? bfhi_m(w) : bflo_m(w);
        } else if (f < 58) {                           // Bg2 split
            int u = f - 46, ks = u >> 1, nt = u & 1;
            int kp = ks * 32 + k, seg = kp >> 5, kk = kp & 31;
            int n = nt * 16 + c;
            bool sPart = (seg < 2) || (seg == 4);
            const float* W = sPart ? rel_hr2 : root_hr2;
            float w = W[kk * 32 + n];
            outv = (seg < 4) ? bfhi_m(w) : bflo_m(w);
        } else if (f < 68) {                           // Bv1
            int n = (f - 58) * 16 + c;
            outv = (n < 150) ? bfhi_m(vn_w1[k * 150 + n]) : 0;
        } else {                                       // Bv2
            int u = f - 68, kt = u / 7, nt = u - kt * 7;
            int kk = kt * 32 + k, n = nt * 16 + c;
            outv = (kk < 150 && n < 100) ? bfhi_m(vn_w2[kk * 100 + n]) : 0;
        }
        pk[t] = (short)outv;
    } else if (t < 52800) {
        int i = t - 52736;
        float* bp = (float*)(pk + 52736);
        bp[i] = (i < 32) ? brel_hr1[i] : brel_rh1[i - 32] + brel_hh1[i - 32];
    } else if (t < 52832) {
        int i = t - 52800;
        float* bp = (float*)(pk + 52864);
        bp[i] = brel_hr2[i];
    }
}

// ---------------------------------------------------------------------------
// Main fused kernel: wave = one batch row. S1 (flipped) -> S2 (flipped) ->
// S4 (flipped) stay ENTIRELY in registers via the kappa K-order trick.
// Per-wave LDS region: 1280 shorts (2.5 KB):
//   XA [0,512) feature staging | SB(s) [512,576) hi/lo | TR(trh) [576,704)
//   RR [704,960) hi/lo | R1 [960,1216) hi/lo | G2(s2) [1216,1280) hi/lo
// Glue (rL2/glue1/glue2) redundant across waves; 2 block barriers.
// ---------------------------------------------------------------------------
__global__ __launch_bounds__(256) void fused_main(
    const float* __restrict__ state, const short* __restrict__ pk,
    const float* __restrict__ wr_w1, const float* __restrict__ wr_b1,
    const float* __restrict__ wr_b2, const float* __restrict__ wh_b2,
    short* __restrict__ r2buf)
{
    __shared__ __align__(16) short wbuf[4 * 1280];

    const int tid = threadIdx.x;
    const int wv = tid >> 6, lane = tid & 63;
    const int q = lane >> 4, c = lane & 15;
    const int b = blockIdx.x * 4 + wv;
    const float* st = state + (size_t)b * 832;
    short* T = wbuf + wv * 1280;
    const short* rowS = wbuf + (c & 3) * 1280;

    const bf16x8* pk16 = (const bf16x8*)pk;
    const float* bg1f = (const float*)(pk + 52736);
    const float* bg2f = (const float*)(pk + 52864);
    const f32x4 z4 = {0.f, 0.f, 0.f, 0.f};

    {   // own human's features -> LDS, B-ready (k=0..6 feats, k=7 -> 1.0)
        float hf[7];
        #pragma unroll
        for (int m = 0; m < 7; ++m) hf[m] = st[lane * 13 + 6 + m];
        uint4 v = make_uint4(pk2(hf[0], hf[1]), pk2(hf[2], hf[3]),
                             pk2(hf[4], hf[5]), pk2(hf[6], 1.0f));
        *(uint4*)(T + lane * 8) = v;
    }

    {   // r-MLP hidden (lane = hidden unit) -> publish trh hi/lo
        float acc = wr_b1[lane];
        #pragma unroll
        for (int m = 0; m < 6; ++m) acc = fmaf(st[m], wr_w1[m * 64 + lane], acc);
        float trh = fmaxf(acc, 0.f);
        unsigned short th = bfhi(trh);
        T[576 + lane] = (short)th;
        T[640 + lane] = (short)bfhi(trh - b2f(th));
    }

    asm volatile("s_waitcnt lgkmcnt(0)" ::: "memory");   // XA visible in-wave

    bf16x8 A1[4], AW2[4];
    #pragma unroll
    for (int i = 0; i < 4; ++i) A1[i] = pk16[i * 64 + lane];
    #pragma unroll
    for (int i = 0; i < 4; ++i) AW2[i] = pk16[(4 + i) * 64 + lane];
    const f32x4 b2v0 = *(const f32x4*)(wh_b2 + 4 * q);
    const f32x4 b2v1 = *(const f32x4*)(wh_b2 + 16 + 4 * q);

    // ---- S1'+S2' fused in registers: t^T = Wh1^T@x^T ; h^T = Wh2^T@t^T ----
    f32x4 sacc0 = z4, sacc1 = z4;
    unsigned hP[16];
    #pragma unroll
    for (int nt = 0; nt < 4; ++nt) {
        bf16x8 bx = zero8();
        if (q == 0) bx = *(const bf16x8*)(T + (nt * 16 + c) * 8);
        // kf0: mh0,mh1
        f32x4 d0 = MFMA16(A1[0], bx, z4);
        f32x4 d1 = MFMA16(A1[1], bx, z4);
        d0 = __builtin_elementwise_max(d0, z4);
        d1 = __builtin_elementwise_max(d1, z4);
        bf16x8 t0 = mk8(pk2(d0[0], d0[1]), pk2(d0[2], d0[3]),
                        pk2(d1[0], d1[1]), pk2(d1[2], d1[3]));
        f32x4 e0 = MFMA16(AW2[0], t0, z4);
        f32x4 e1 = MFMA16(AW2[2], t0, z4);
        // kf1: mh2,mh3
        f32x4 d2 = MFMA16(A1[2], bx, z4);
        f32x4 d3 = MFMA16(A1[3], bx, z4);
        d2 = __builtin_elementwise_max(d2, z4);
        d3 = __builtin_elementwise_max(d3, z4);
        bf16x8 t1 = mk8(pk2(d2[0], d2[1]), pk2(d2[2], d2[3]),
                        pk2(d3[0], d3[1]), pk2(d3[2], d3[3]));
        e0 = MFMA16(AW2[1], t1, e0);
        e1 = MFMA16(AW2[3], t1, e1);
        e0 = __builtin_elementwise_max(e0 + b2v0, z4);
        e1 = __builtin_elementwise_max(e1 + b2v1, z4);
        sacc0 += e0; sacc1 += e1;
        hP[nt * 4 + 0] = pk2(e0[0], e0[1]); hP[nt * 4 + 1] = pk2(e0[2], e0[3]);
        hP[nt * 4 + 2] = pk2(e1[0], e1[1]); hP[nt * 4 + 3] = pk2(e1[2], e1[3]);
    }
    // s = sum over humans: reduce across c-lanes (bits 0..3)
    #pragma unroll
    for (int mask = 1; mask <= 8; mask <<= 1) {
        #pragma unroll
        for (int r = 0; r < 4; ++r) {
            sacc0[r] += __shfl_xor(sacc0[r], mask);
            sacc1[r] += __shfl_xor(sacc1[r], mask);
        }
    }
    if (c == 0) {   // publish s hi/lo (feats fo*16+4q+r)
        *(unsigned*)(T + 512 + 4 * q)          = pk2(sacc0[0], sacc0[1]);
        *(unsigned*)(T + 512 + 4 * q + 2)      = pk2(sacc0[2], sacc0[3]);
        *(unsigned*)(T + 512 + 16 + 4 * q)     = pk2(sacc1[0], sacc1[1]);
        *(unsigned*)(T + 512 + 16 + 4 * q + 2) = pk2(sacc1[2], sacc1[3]);
        *(unsigned*)(T + 544 + 4 * q)          = pk2(lof(sacc0[0]), lof(sacc0[1]));
        *(unsigned*)(T + 544 + 4 * q + 2)      = pk2(lof(sacc0[2]), lof(sacc0[3]));
        *(unsigned*)(T + 544 + 16 + 4 * q)     = pk2(lof(sacc1[0]), lof(sacc1[1]));
        *(unsigned*)(T + 544 + 16 + 4 * q + 2) = pk2(lof(sacc1[2]), lof(sacc1[3]));
    }
    __syncthreads();   // B1: s + trh of all 4 rows visible

    // ---- rL2 (all waves, redundant): rr rows 0..3, split-bf16 K=192 ----
    {
        bf16x8 at0 = *(const bf16x8*)(rowS + 576 + q * 8);   // t_hi k0..31
        bf16x8 at1 = *(const bf16x8*)(rowS + 608 + q * 8);   // t_hi k32..63
        bf16x8 at2 = *(const bf16x8*)(rowS + 640 + q * 8);   // t_lo k0..31
        bf16x8 at3 = *(const bf16x8*)(rowS + 672 + q * 8);   // t_lo k32..63
        f32x4 dr0 = z4, dr1 = z4;
        dr0 = MFMA16(at0, pk16[10 * 64 + lane], dr0); dr1 = MFMA16(at0, pk16[11 * 64 + lane], dr1);
        dr0 = MFMA16(at1, pk16[12 * 64 + lane], dr0); dr1 = MFMA16(at1, pk16[13 * 64 + lane], dr1);
        dr0 = MFMA16(at2, pk16[14 * 64 + lane], dr0); dr1 = MFMA16(at2, pk16[15 * 64 + lane], dr1);
        dr0 = MFMA16(at3, pk16[16 * 64 + lane], dr0); dr1 = MFMA16(at3, pk16[17 * 64 + lane], dr1);
        dr0 = MFMA16(at0, pk16[18 * 64 + lane], dr0); dr1 = MFMA16(at0, pk16[19 * 64 + lane], dr1);
        dr0 = MFMA16(at1, pk16[20 * 64 + lane], dr0); dr1 = MFMA16(at1, pk16[21 * 64 + lane], dr1);
        const float wb0 = wr_b2[c], wb1 = wr_b2[16 + c];
        if (q == 0) {
            #pragma unroll
            for (int r = 0; r < 4; ++r) {
                float v0 = fmaxf(dr0[r] + wb0, 0.f), v1 = fmaxf(dr1[r] + wb1, 0.f);
                unsigned short h0 = bfhi(v0), h1 = bfhi(v1);
                T[704 + r * 32 + c]      = (short)h0;
                T[704 + r * 32 + 16 + c] = (short)h1;
                T[832 + r * 32 + c]      = (short)bfhi(v0 - b2f(h0));
                T[832 + r * 32 + 16 + c] = (short)bfhi(v1 - b2f(h1));
            }
        }
    }
    asm volatile("s_waitcnt lgkmcnt(0)" ::: "memory");

    // ---- glue1 (all waves): r1 + c1 rows 0..3 ----
    f32x4 c1f0, c1f1;
    {
        bf16x8 as0 = *(const bf16x8*)(rowS + 512 + q * 8);             // s_hi
        bf16x8 as1 = *(const bf16x8*)(rowS + 544 + q * 8);             // s_lo
        bf16x8 ar0 = *(const bf16x8*)(T + 704 + (c & 3) * 32 + q * 8); // r_hi
        bf16x8 ar1 = *(const bf16x8*)(T + 832 + (c & 3) * 32 + q * 8); // r_lo
        f32x4 dg[4] = {z4, z4, z4, z4};
        #pragma unroll
        for (int nt = 0; nt < 4; ++nt) dg[nt] = MFMA16(as0, pk16[(22 +  0 + nt) * 64 + lane], dg[nt]);
        #pragma unroll
        for (int nt = 0; nt < 4; ++nt) dg[nt] = MFMA16(as1, pk16[(22 +  4 + nt) * 64 + lane], dg[nt]);
        #pragma unroll
        for (int nt = 0; nt < 4; ++nt) dg[nt] = MFMA16(ar0, pk16[(22 +  8 + nt) * 64 + lane], dg[nt]);
        #pragma unroll
        for (int nt = 0; nt < 4; ++nt) dg[nt] = MFMA16(ar1, pk16[(22 + 12 + nt) * 64 + lane], dg[nt]);
        #pragma unroll
        for (int nt = 0; nt < 4; ++nt) dg[nt] = MFMA16(as0, pk16[(22 + 16 + nt) * 64 + lane], dg[nt]);
        #pragma unroll
        for (int nt = 0; nt < 4; ++nt) dg[nt] = MFMA16(ar0, pk16[(22 + 20 + nt) * 64 + lane], dg[nt]);
        // c1 for OWN row: batch rows live at lanes 0..15 (reg=wv), col=4q+r
        #pragma unroll
        for (int r = 0; r < 4; ++r) {
            c1f0[r] = __shfl(dg[2][wv], 4 * q + r);
            c1f1[r] = __shfl(dg[3][wv], 4 * q + r);
        }
        c1f0 += *(const f32x4*)(bg1f + 32 + 4 * q);
        c1f1 += *(const f32x4*)(bg1f + 48 + 4 * q);
        if (q == 0) {   // r1 (relu+bias) -> own R1 hi/lo
            const float gb0 = bg1f[c], gb1 = bg1f[16 + c];
            #pragma unroll
            for (int r = 0; r < 4; ++r) {
                float v0 = fmaxf(dg[0][r] + gb0, 0.f), v1 = fmaxf(dg[1][r] + gb1, 0.f);
                unsigned short h0 = bfhi(v0), h1 = bfhi(v1);
                T[960 + r * 32 + c]       = (short)h0;
                T[960 + r * 32 + 16 + c]  = (short)h1;
                T[1088 + r * 32 + c]      = (short)bfhi(v0 - b2f(h0));
                T[1088 + r * 32 + 16 + c] = (short)bfhi(v1 - b2f(h1));
            }
        }
    }

    // ---- S4' in registers: s2^T = sum_hu relu(c1 + W1eff^T @ h^T) ----
    {
        bf16x8 AWe0 = pk16[8 * 64 + lane], AWe1 = pk16[9 * 64 + lane];
        f32x4 s2a0 = z4, s2a1 = z4;
        #pragma unroll
        for (int nt = 0; nt < 4; ++nt) {
            bf16x8 hb = mk8(hP[nt * 4 + 0], hP[nt * 4 + 1], hP[nt * 4 + 2], hP[nt * 4 + 3]);
            f32x4 g0 = MFMA16(AWe0, hb, z4);
            f32x4 g1 = MFMA16(AWe1, hb, z4);
            s2a0 += __builtin_elementwise_max(g0 + c1f0, z4);
            s2a1 += __builtin_elementwise_max(g1 + c1f1, z4);
        }
        #pragma unroll
        for (int mask = 1; mask <= 8; mask <<= 1) {
            #pragma unroll
            for (int r = 0; r < 4; ++r) {
                s2a0[r] += __shfl_xor(s2a0[r], mask);
                s2a1[r] += __shfl_xor(s2a1[r], mask);
            }
        }
        if (c == 0) {   // publish s2 hi/lo (outs ot*16+4q+r)
            *(unsigned*)(T + 1216 + 4 * q)          = pk2(s2a0[0], s2a0[1]);
            *(unsigned*)(T + 1216 + 4 * q + 2)      = pk2(s2a0[2], s2a0[3]);
            *(unsigned*)(T + 1216 + 16 + 4 * q)     = pk2(s2a1[0], s2a1[1]);
            *(unsigned*)(T + 1216 + 16 + 4 * q + 2) = pk2(s2a1[2], s2a1[3]);
            *(unsigned*)(T + 1248 + 4 * q)          = pk2(lof(s2a0[0]), lof(s2a0[1]));
            *(unsigned*)(T + 1248 + 4 * q + 2)      = pk2(lof(s2a0[2]), lof(s2a0[3]));
            *(unsigned*)(T + 1248 + 16 + 4 * q)     = pk2(lof(s2a1[0]), lof(s2a1[1]));
            *(unsigned*)(T + 1248 + 16 + 4 * q + 2) = pk2(lof(s2a1[2]), lof(s2a1[3]));
        }
    }
    __syncthreads();   // B2: s2 of all 4 rows visible

    {   // ---- glue2 (all waves) -> own row's r2 ----
        bf16x8 ag0  = *(const bf16x8*)(rowS + 1216 + q * 8);            // s2_hi
        bf16x8 ag1  = *(const bf16x8*)(rowS + 1248 + q * 8);            // s2_lo
        bf16x8 agr0 = *(const bf16x8*)(T + 960 + (c & 3) * 32 + q * 8);  // r1_hi
        bf16x8 agr1 = *(const bf16x8*)(T + 1088 + (c & 3) * 32 + q * 8); // r1_lo
        f32x4 d0 = z4, d1 = z4;
        d0 = MFMA16(ag0,  pk16[46 * 64 + lane], d0); d1 = MFMA16(ag0,  pk16[47 * 64 + lane], d1);
        d0 = MFMA16(ag1,  pk16[48 * 64 + lane], d0); d1 = MFMA16(ag1,  pk16[49 * 64 + lane], d1);
        d0 = MFMA16(agr0, pk16[50 * 64 + lane], d0); d1 = MFMA16(agr0, pk16[51 * 64 + lane], d1);
        d0 = MFMA16(agr1, pk16[52 * 64 + lane], d0); d1 = MFMA16(agr1, pk16[53 * 64 + lane], d1);
        d0 = MFMA16(ag0,  pk16[54 * 64 + lane], d0); d1 = MFMA16(ag0,  pk16[55 * 64 + lane], d1);
        d0 = MFMA16(agr0, pk16[56 * 64 + lane], d0); d1 = MFMA16(agr0, pk16[57 * 64 + lane], d1);
        if (q == 0) {
            const float g0 = bg2f[c], g1 = bg2f[16 + c];
            r2buf[b * 32 + c]      = f2s(fmaxf(d0[wv] + g0, 0.f));
            r2buf[b * 32 + 16 + c] = f2s(fmaxf(d1[wv] + g1, 0.f));
        }
    }
}

// ---------------------------------------------------------------------------
__global__ __launch_bounds__(256) void head_kernel(
    const short* __restrict__ pk,
    const float* __restrict__ vn_b1, const float* __restrict__ vn_b2,
    const float* __restrict__ vn_w3, const float* __restrict__ vn_b3,
    float* __restrict__ out)
{
    __shared__ __align__(16) short sh_v1[4][16 * 168];
    const int wv = threadIdx.x >> 6, lane = threadIdx.x & 63;
    const int q = lane >> 4, c = lane & 15;
    const int tile = blockIdx.x * 4 + wv;
    const bf16x8* wf = (const bf16x8*)pk;
    const short* r2b = pk + 53248;
    const f32x4 z4 = {0.f, 0.f, 0.f, 0.f};

    bf16x8 a1 = *(const bf16x8*)&r2b[(tile * 16 + c) * 32 + q * 8];
    short* vb = sh_v1[wv];
    #pragma unroll
    for (int nt = 0; nt < 10; ++nt) {
        f32x4 d = MFMA16(a1, wf[(58 + nt) * 64 + lane], z4);
        int n = nt * 16 + c;
        float bias = (n < 150) ? vn_b1[n] : 0.f;
        #pragma unroll
        for (int r = 0; r < 4; ++r) {
            float v = (n < 150) ? fmaxf(d[r] + bias, 0.f) : 0.f;
            vb[(q * 4 + r) * 168 + n] = f2s(v);
        }
    }
    __syncthreads();

    bf16x8 a2[5];
    #pragma unroll
    for (int kt = 0; kt < 5; ++kt)
        a2[kt] = *(const bf16x8*)&vb[c * 168 + kt * 32 + q * 8];

    float racc[4] = {0.f, 0.f, 0.f, 0.f};
    #pragma unroll
    for (int nt = 0; nt < 7; ++nt) {
        f32x4 d = z4;
        #pragma unroll
        for (int kt = 0; kt < 5; ++kt)
            d = MFMA16(a2[kt], wf[(68 + kt * 7 + nt) * 64 + lane], d);
        int n = nt * 16 + c;
        float bias = (n < 100) ? vn_b2[n] : 0.f;
        float w3   = (n < 100) ? vn_w3[n] : 0.f;
        #pragma unroll
        for (int r = 0; r < 4; ++r) racc[r] += fmaxf(d[r] + bias, 0.f) * w3;
    }
    #pragma unroll
    for (int m = 1; m < 16; m <<= 1) {
        #pragma unroll
        for (int r = 0; r < 4; ++r) racc[r] += __shfl_xor(racc[r], m);
    }
    if (c == 0) {
        float b3 = vn_b3[0];
        #pragma unroll
        for (int r = 0; r < 4; ++r) out[tile * 16 + q * 4 + r] = racc[r] + b3;
    }
}

// ---------------------------------------------------------------------------
extern "C" void kernel_launch(void* const* d_in, const int* in_sizes, int n_in,
                              void* d_out, int out_size, void* d_ws, size_t ws_size,
                              hipStream_t stream) {
    const float* state    = (const float*)d_in[0];
    const float* wr_w1    = (const float*)d_in[2];
    const float* wr_b1    = (const float*)d_in[3];
    const float* wr_w2    = (const float*)d_in[4];
    const float* wr_b2    = (const float*)d_in[5];
    const float* wh_w1    = (const float*)d_in[6];
    const float* wh_b1    = (const float*)d_in[7];
    const float* wh_w2    = (const float*)d_in[8];
    const float* wh_b2    = (const float*)d_in[9];
    const float* rel_rh1  = (const float*)d_in[10];
    const float* brel_rh1 = (const float*)d_in[11];
    const float* root_rh1 = (const float*)d_in[12];
    const float* rel_hr1  = (const float*)d_in[13];
    const float* brel_hr1 = (const float*)d_in[14];
    const float* root_hr1 = (const float*)d_in[15];
    const float* rel_hh1  = (const float*)d_in[16];
    const float* brel_hh1 = (const float*)d_in[17];
    const float* root_hh1 = (const float*)d_in[18];
    // 19..21, 25..27 dead (layer-2 new_h unused)
    const float* rel_hr2  = (const float*)d_in[22];
    const float* brel_hr2 = (const float*)d_in[23];
    const float* root_hr2 = (const float*)d_in[24];
    const float* vn_w1    = (const float*)d_in[28];
    const float* vn_b1    = (const float*)d_in[29];
    const float* vn_w2    = (const float*)d_in[30];
    const float* vn_b2    = (const float*)d_in[31];
    const float* vn_w3    = (const float*)d_in[32];
    const float* vn_b3    = (const float*)d_in[33];
    float* out = (float*)d_out;
    short* pk  = (short*)d_ws;               // needs ~1.16 MB of workspace
    short* r2buf = pk + 53248;

    pack_frags<<<207, 256, 0, stream>>>(wh_w1, wh_b1, wh_w2,
                                        root_rh1, root_hh1, rel_hh1, wr_w2,
                                        rel_hr1, root_hr1, rel_rh1,
                                        rel_hr2, root_hr2, vn_w1, vn_w2,
                                        brel_hr1, brel_rh1, brel_hh1, brel_hr2, pk);
    fused_main<<<BTOT / 4, 256, 0, stream>>>(state, pk, wr_w1, wr_b1, wr_b2, wh_b2, r2buf);
    head_kernel<<<BTOT / 64, 256, 0, stream>>>(pk, vn_b1, vn_b2, vn_w3, vn_b3, out);
}

// Round 9
// 195.091 us; speedup vs baseline: 1.0271x; 1.0271x over previous
//
#include <hip/hip_runtime.h>

#define BTOT 16384

typedef __attribute__((ext_vector_type(8))) short bf16x8;   // 8 bf16 in 4 VGPRs
typedef __attribute__((ext_vector_type(4))) float f32x4;

#define MFMA16(a,b,c) __builtin_amdgcn_mfma_f32_16x16x32_bf16((a),(b),(c),0,0,0)

// ---- bf16 conversion helpers: HW packed cvt if available, manual RNE else ----
#if __has_builtin(__builtin_amdgcn_cvt_pk_bf16_f32)
typedef __attribute__((ext_vector_type(2))) __bf16 hwbf2;
static __device__ __forceinline__ unsigned pk2(float a, float b) {
    hwbf2 v = __builtin_amdgcn_cvt_pk_bf16_f32(a, b);
    return __builtin_bit_cast(unsigned, v);
}
#else
static __device__ __forceinline__ unsigned pk2(float a, float b) {
    unsigned ua = __float_as_uint(a), ub = __float_as_uint(b);
    unsigned ra = (ua + 0x7FFFu + ((ua >> 16) & 1u)) >> 16;
    unsigned rb = (ub + 0x7FFFu + ((ub >> 16) & 1u)) >> 16;
    return (ra & 0xFFFFu) | (rb << 16);
}
#endif
static __device__ __forceinline__ unsigned short bfhi(float x) {
    return (unsigned short)(pk2(x, 0.f) & 0xFFFFu);
}
static __device__ __forceinline__ float b2f(unsigned short h) {
    return __uint_as_float(((unsigned)h) << 16);
}
static __device__ __forceinline__ short f2s(float x) { return (short)bfhi(x); }
// manual RNE for the pack kernel (identical rounding either path)
static __device__ __forceinline__ unsigned short bfhi_m(float x) {
    unsigned u = __float_as_uint(x);
    return (unsigned short)((u + 0x7FFFu + ((u >> 16) & 1u)) >> 16);
}
static __device__ __forceinline__ unsigned short bflo_m(float x) {
    unsigned short h = bfhi_m(x);
    return bfhi_m(x - b2f(h));
}
static __device__ __forceinline__ bf16x8 zero8() {
    bf16x8 v;
    #pragma unroll
    for (int i = 0; i < 8; ++i) v[i] = 0;
    return v;
}

// ---------------------------------------------------------------------------
// Workspace (shorts). Frags are 512 shorts each, frag f at pk[f*512 + lane*8 + j].
// f 0..3 A1 | 4..7 Bh2 (K-order matched to paired-b128 t storage) |
// 8..9 Be (K-permuted: k_old=(k>>1)+((k&1)<<4)) | 10..21 BrL2(split K=192) |
// 22..45 Bg1(split) | 46..57 Bg2(split) | 58..67 Bv1 | 68..102 Bv2.
// shorts 52736..52864: bg1 f32[64]; 52864..52928: bg2 f32[32]. ~106 KB.
// ---------------------------------------------------------------------------
__global__ void pack_frags(
    const float* __restrict__ wh_w1, const float* __restrict__ wh_b1,
    const float* __restrict__ wh_w2,
    const float* __restrict__ root_rh1, const float* __restrict__ root_hh1,
    const float* __restrict__ rel_hh1,
    const float* __restrict__ wr_w2,
    const float* __restrict__ rel_hr1, const float* __restrict__ root_hr1,
    const float* __restrict__ rel_rh1,
    const float* __restrict__ rel_hr2, const float* __restrict__ root_hr2,
    const float* __restrict__ vn_w1, const float* __restrict__ vn_w2,
    const float* __restrict__ brel_hr1, const float* __restrict__ brel_rh1,
    const float* __restrict__ brel_hh1, const float* __restrict__ brel_hr2,
    short* __restrict__ pk)
{
    int t = blockIdx.x * blockDim.x + threadIdx.x;
    if (t < 52736) {
        int f = t >> 9, r = t & 511;
        int lane = r >> 3, j = r & 7;
        int q = lane >> 4, c = lane & 15;
        int k = q * 8 + j;
        unsigned short outv;
        if (f < 4) {                                   // A1: Wh1^T (+bias row k=7)
            int m = f * 16 + c;
            float v = (k < 7) ? wh_w1[k * 64 + m] : (k == 7 ? wh_b1[m] : 0.f);
            outv = bfhi_m(v);
        } else if (f < 8) {                            // Bh2; K-order for paired t
            int u = f - 4, ks = u >> 1, nt = u & 1;
            int kr = ks * 32 + (j >> 2) * 16 + q * 4 + (j & 3);
            outv = bfhi_m(wh_w2[kr * 32 + nt * 16 + c]);
        } else if (f < 10) {                           // Be (W1eff), K-permuted for
            int n = (f - 8) * 16 + c;                  // interleaved h layout
            int ko = (k >> 1) + ((k & 1) << 4);
            outv = bfhi_m(root_rh1[ko * 32 + n] + root_hh1[ko * 32 + n] - rel_hh1[ko * 32 + n]);
        } else if (f < 22) {                           // BrL2 split
            int u = f - 10, ks = u >> 1, nt = u & 1;
            int kp = ks * 32 + k;                      // 0..191
            float w = wr_w2[(kp & 63) * 32 + nt * 16 + c];
            outv = (kp < 128) ? bfhi_m(w) : bflo_m(w);
        } else if (f < 46) {                           // Bg1 split
            int u = f - 22, ks = u >> 2, nt = u & 3;
            int kp = ks * 32 + k, seg = kp >> 5, kk = kp & 31;
            int n2 = (nt & 1) * 16 + c;
            bool sPart = (seg < 2) || (seg == 4);
            const float* W = (nt < 2) ? (sPart ? rel_hr1 : root_hr1)
                                      : (sPart ? rel_hh1 : rel_rh1);
            float w = W[kk * 32 + n2];
            outv = (seg < 4) ? bfhi_m(w) : bflo_m(w);
        } else if (f < 58) {                           // Bg2 split
            int u = f - 46, ks = u >> 1, nt = u & 1;
            int kp = ks * 32 + k, seg = kp >> 5, kk = kp & 31;
            int n = nt * 16 + c;
            bool sPart = (seg < 2) || (seg == 4);
            const float* W = sPart ? rel_hr2 : root_hr2;
            float w = W[kk * 32 + n];
            outv = (seg < 4) ? bfhi_m(w) : bflo_m(w);
        } else if (f < 68) {                           // Bv1
            int n = (f - 58) * 16 + c;
            outv = (n < 150) ? bfhi_m(vn_w1[k * 150 + n]) : 0;
        } else {                                       // Bv2
            int u = f - 68, kt = u / 7, nt = u - kt * 7;
            int kk = kt * 32 + k, n = nt * 16 + c;
            outv = (kk < 150 && n < 100) ? bfhi_m(vn_w2[kk * 100 + n]) : 0;
        }
        pk[t] = (short)outv;
    } else if (t < 52800) {
        int i = t - 52736;
        float* bp = (float*)(pk + 52736);
        bp[i] = (i < 32) ? brel_hr1[i] : brel_rh1[i - 32] + brel_hh1[i - 32];
    } else if (t < 52832) {
        int i = t - 52800;
        float* bp = (float*)(pk + 52864);
        bp[i] = brel_hr2[i];
    }
}

// ---------------------------------------------------------------------------
// Fully fused kernel (R6 structure + head). Wave = one batch row.
// Per-wave T[4096 shorts] (8 KB): t rows (row*64, b128 swizzle), h rows
// (row*32, interleaved, swizzle row&3), tail overlays c1@3456 g2in@3520
// sbuf@3712 trh@3904. Head buffers live in wave0's dead h-region:
//   R2 @ wbuf[0][0..128) | V1 @ wbuf[0][128..768) | partial f32[16] @ [768..800)
// Barriers: B1(s,trh) B2(c1,r1) B3(s2) B4(r2) B5(v1) B6(partials).
// ---------------------------------------------------------------------------
__global__ __launch_bounds__(256) void fused_main(
    const float* __restrict__ state, const short* __restrict__ pk,
    const float* __restrict__ wr_w1, const float* __restrict__ wr_b1,
    const float* __restrict__ wr_b2, const float* __restrict__ wh_b2,
    const float* __restrict__ vn_b1, const float* __restrict__ vn_b2,
    const float* __restrict__ vn_w3, const float* __restrict__ vn_b3,
    float* __restrict__ out)
{
    __shared__ __align__(16) short wbuf[4][4096];

    const int tid = threadIdx.x;
    const int wv = tid >> 6, lane = tid & 63;
    const int q = lane >> 4, c = lane & 15;
    const int b = blockIdx.x * 4 + wv;
    const float* st = state + (size_t)b * 832;
    short* T = wbuf[wv];

    const bf16x8* pk16 = (const bf16x8*)pk;
    const float* bg1f = (const float*)(pk + 52736);
    const float* bg2f = (const float*)(pk + 52864);
    const f32x4 z4 = {0.f, 0.f, 0.f, 0.f};

    bf16x8 A1[4], Bh2v[4], Bev[2];
    #pragma unroll
    for (int i = 0; i < 4; ++i) A1[i] = pk16[i * 64 + lane];
    #pragma unroll
    for (int i = 0; i < 4; ++i) Bh2v[i] = pk16[(4 + i) * 64 + lane];
    #pragma unroll
    for (int i = 0; i < 2; ++i) Bev[i] = pk16[(8 + i) * 64 + lane];

    {   // own human's features -> LDS, B-ready (k=0..6 feats, k=7 -> 1.0)
        float hf[7];
        #pragma unroll
        for (int m = 0; m < 7; ++m) hf[m] = st[lane * 13 + 6 + m];
        uint4 v = make_uint4(pk2(hf[0], hf[1]), pk2(hf[2], hf[3]),
                             pk2(hf[4], hf[5]), pk2(hf[6], 1.0f));
        *(uint4*)(T + lane * 8) = v;
    }

    float trh;   // r-MLP hidden (lane = hidden unit)
    {
        float acc = wr_b1[lane];
        #pragma unroll
        for (int m = 0; m < 6; ++m) acc = fmaf(st[m], wr_w1[m * 64 + lane], acc);
        trh = fmaxf(acc, 0.f);
    }

    asm volatile("s_waitcnt lgkmcnt(0)" ::: "memory");

    bf16x8 bx[4];
    #pragma unroll
    for (int ht = 0; ht < 4; ++ht) {
        bf16x8 v = zero8();
        if (q == 0) v = *(const bf16x8*)(T + (ht * 16 + c) * 8);
        bx[ht] = v;
    }

    // S1': t^T = Wh1^T @ x^T; paired mh tiles -> one b128 write per (mhp,ht)
    #pragma unroll
    for (int mhp = 0; mhp < 2; ++mhp) {
        #pragma unroll
        for (int ht = 0; ht < 4; ++ht) {
            f32x4 d0 = MFMA16(A1[2 * mhp + 0], bx[ht], z4);
            f32x4 d1 = MFMA16(A1[2 * mhp + 1], bx[ht], z4);
            d0 = __builtin_elementwise_max(d0, z4);
            d1 = __builtin_elementwise_max(d1, z4);
            uint4 w = make_uint4(pk2(d0[0], d0[1]), pk2(d0[2], d0[3]),
                                 pk2(d1[0], d1[1]), pk2(d1[2], d1[3]));
            int row = ht * 16 + c;
            int p = (mhp * 4 + q) ^ (c & 7);
            *(uint4*)(T + row * 64 + p * 8) = w;
        }
    }

    asm volatile("s_waitcnt lgkmcnt(0)" ::: "memory");

    // S2: h = t @ Wh2 (+b2, relu); packed-pair h rows + vector s-accumulators
    const float b2a = wh_b2[c], b2b = wh_b2[16 + c];
    const f32x4 b2a4 = {b2a, b2a, b2a, b2a}, b2b4 = {b2b, b2b, b2b, b2b};
    f32x4 psv0 = z4, psv1 = z4;
    #pragma unroll
    for (int mt = 0; mt < 4; ++mt) {
        int row = mt * 16 + c;
        bf16x8 a0 = *(const bf16x8*)(T + row * 64 + ((q ^ (c & 7))) * 8);
        bf16x8 a1 = *(const bf16x8*)(T + row * 64 + (((q + 4) ^ (c & 7))) * 8);
        f32x4 e0 = MFMA16(a0, Bh2v[0], z4); e0 = MFMA16(a1, Bh2v[2], e0);
        f32x4 e1 = MFMA16(a0, Bh2v[1], z4); e1 = MFMA16(a1, Bh2v[3], e1);
        e0 = __builtin_elementwise_max(e0 + b2a4, z4);
        e1 = __builtin_elementwise_max(e1 + b2b4, z4);
        psv0 += e0; psv1 += e1;
        #pragma unroll
        for (int r = 0; r < 4; ++r) {
            int hrow = mt * 16 + q * 4 + r;
            *(unsigned*)(T + hrow * 32 + (((c >> 2) ^ r)) * 8 + (c & 3) * 2) = pk2(e0[r], e1[r]);
        }
    }
    float ps0 = (psv0[0] + psv0[1]) + (psv0[2] + psv0[3]);
    float ps1 = (psv1[0] + psv1[1]) + (psv1[2] + psv1[3]);
    ps0 += __shfl_xor(ps0, 16); ps0 += __shfl_xor(ps0, 32);
    ps1 += __shfl_xor(ps1, 16); ps1 += __shfl_xor(ps1, 32);

    {   // s -> sbuf: [s_hi;s_lo;r_hi;r_lo;s_hi;r_hi], trh -> [hi;lo;hi]
        short* SB = T + 3712;
        if (q == 0) {
            unsigned short h0 = bfhi(ps0), h1 = bfhi(ps1);
            SB[c] = (short)h0;        SB[16 + c] = (short)h1;
            SB[32 + c] = (short)bfhi(ps0 - b2f(h0));
            SB[48 + c] = (short)bfhi(ps1 - b2f(h1));
            SB[128 + c] = (short)h0;  SB[144 + c] = (short)h1;
        }
        short* TR = T + 3904;
        unsigned short th = bfhi(trh);
        TR[lane] = (short)th;
        TR[64 + lane] = (short)bfhi(trh - b2f(th));
        TR[128 + lane] = (short)th;
    }
    __syncthreads();   // B1

    if (wv == 0) {     // rL2 + glue1 for the block's 4 rows (split-bf16 K=192)
        bf16x8 art[6];
        #pragma unroll
        for (int ks = 0; ks < 6; ++ks) {
            bf16x8 v = zero8();
            if (c < 4) v = *(const bf16x8*)(wbuf[c] + 3904 + ks * 32 + q * 8);
            art[ks] = v;
        }
        f32x4 dr0 = z4, dr1 = z4;
        #pragma unroll
        for (int ks = 0; ks < 6; ++ks) {
            dr0 = MFMA16(art[ks], pk16[(10 + ks * 2 + 0) * 64 + lane], dr0);
            dr1 = MFMA16(art[ks], pk16[(10 + ks * 2 + 1) * 64 + lane], dr1);
        }
        const float wb0 = wr_b2[c], wb1 = wr_b2[16 + c];
        if (q == 0) {
            #pragma unroll
            for (int r = 0; r < 4; ++r) {
                float v0 = fmaxf(dr0[r] + wb0, 0.f), v1 = fmaxf(dr1[r] + wb1, 0.f);
                short* SBr = wbuf[r] + 3712;
                unsigned short h0 = bfhi(v0), h1 = bfhi(v1);
                SBr[64 + c] = (short)h0;  SBr[96 + c]  = (short)bfhi(v0 - b2f(h0));  SBr[160 + c] = (short)h0;
                SBr[80 + c] = (short)h1;  SBr[112 + c] = (short)bfhi(v1 - b2f(h1));  SBr[176 + c] = (short)h1;
            }
        }
        asm volatile("s_waitcnt lgkmcnt(0)" ::: "memory");

        bf16x8 ag[6];
        #pragma unroll
        for (int ks = 0; ks < 6; ++ks) {
            bf16x8 v = zero8();
            if (c < 4) v = *(const bf16x8*)(wbuf[c] + 3712 + ks * 32 + q * 8);
            ag[ks] = v;
        }
        f32x4 dg[4] = {z4, z4, z4, z4};
        #pragma unroll
        for (int ks = 0; ks < 6; ++ks) {
            #pragma unroll
            for (int nt = 0; nt < 4; ++nt)
                dg[nt] = MFMA16(ag[ks], pk16[(22 + ks * 4 + nt) * 64 + lane], dg[nt]);
        }
        if (q == 0) {
            #pragma unroll
            for (int nt = 0; nt < 2; ++nt) {
                float bias = bg1f[nt * 16 + c];
                #pragma unroll
                for (int r = 0; r < 4; ++r) {       // r1 -> g2in
                    float v = fmaxf(dg[nt][r] + bias, 0.f);
                    short* G2r = wbuf[r] + 3520;
                    unsigned short hh = bfhi(v);
                    G2r[64 + nt * 16 + c]  = (short)hh;
                    G2r[96 + nt * 16 + c]  = (short)bfhi(v - b2f(hh));
                    G2r[160 + nt * 16 + c] = (short)hh;
                }
            }
            #pragma unroll
            for (int nt = 2; nt < 4; ++nt) {
                float bias = bg1f[nt * 16 + c];
                #pragma unroll
                for (int r = 0; r < 4; ++r)         // c1 (f32, no relu)
                    ((float*)(wbuf[r] + 3456))[(nt - 2) * 16 + c] = dg[nt][r] + bias;
            }
        }
    }
    __syncthreads();   // B2

    {   // S4: s2 = sum_hu relu(c1 + h @ W1eff)   (h interleaved, Be K-permuted)
        const float* C1 = (const float*)(T + 3456);
        const float c10 = C1[c], c11 = C1[16 + c];
        const f32x4 c10v = {c10, c10, c10, c10}, c11v = {c11, c11, c11, c11};
        f32x4 acc0 = z4, acc1 = z4;
        #pragma unroll
        for (int mt = 0; mt < 4; ++mt) {
            int row = mt * 16 + c;
            bf16x8 ah = *(const bf16x8*)(T + row * 32 + ((q ^ (c & 3))) * 8);
            f32x4 g0 = MFMA16(ah, Bev[0], z4);
            f32x4 g1 = MFMA16(ah, Bev[1], z4);
            acc0 += __builtin_elementwise_max(g0 + c10v, z4);
            acc1 += __builtin_elementwise_max(g1 + c11v, z4);
        }
        float t0 = (acc0[0] + acc0[1]) + (acc0[2] + acc0[3]);
        float t1 = (acc1[0] + acc1[1]) + (acc1[2] + acc1[3]);
        t0 += __shfl_xor(t0, 16); t0 += __shfl_xor(t0, 32);
        t1 += __shfl_xor(t1, 16); t1 += __shfl_xor(t1, 32);
        short* G2 = T + 3520;   // [s2_hi(32); s2_lo(32); r1...; s2_hi(32); r1...]
        if (q == 0) {
            unsigned short h0 = bfhi(t0), h1 = bfhi(t1);
            G2[c] = (short)h0;        G2[16 + c] = (short)h1;
            G2[32 + c] = (short)bfhi(t0 - b2f(h0));
            G2[48 + c] = (short)bfhi(t1 - b2f(h1));
            G2[128 + c] = (short)h0;  G2[144 + c] = (short)h1;
        }
    }
    __syncthreads();   // B3

    short* HB = wbuf[0];          // head buffers in dead h-region of wave 0
    if (wv == 0) {     // glue2 -> r2 -> LDS (R2 @ HB[0..128))
        bf16x8 a2[6];
        #pragma unroll
        for (int ks = 0; ks < 6; ++ks) {
            bf16x8 v = zero8();
            if (c < 4) v = *(const bf16x8*)(wbuf[c] + 3520 + ks * 32 + q * 8);
            a2[ks] = v;
        }
        f32x4 d0 = z4, d1 = z4;
        #pragma unroll
        for (int ks = 0; ks < 6; ++ks) {
            d0 = MFMA16(a2[ks], pk16[(46 + ks * 2 + 0) * 64 + lane], d0);
            d1 = MFMA16(a2[ks], pk16[(46 + ks * 2 + 1) * 64 + lane], d1);
        }
        if (q == 0) {
            const float g0 = bg2f[c], g1 = bg2f[16 + c];
            #pragma unroll
            for (int r = 0; r < 4; ++r) {
                HB[r * 32 + c]      = f2s(fmaxf(d0[r] + g0, 0.f));
                HB[r * 32 + 16 + c] = f2s(fmaxf(d1[r] + g1, 0.f));
            }
        }
    }
    __syncthreads();   // B4: r2 visible

    // ---- head v1: all waves, split the 10 n-tiles (rows replicated x4) ----
    {
        bf16x8 ar2 = *(const bf16x8*)(HB + (c & 3) * 32 + q * 8);
        for (int nt = wv; nt < 10; nt += 4) {
            f32x4 d = MFMA16(ar2, pk16[(58 + nt) * 64 + lane], z4);
            int n = nt * 16 + c;
            float bias = (n < 150) ? vn_b1[n] : 0.f;
            if (q == 0) {
                #pragma unroll
                for (int r = 0; r < 4; ++r) {
                    float v = (n < 150) ? fmaxf(d[r] + bias, 0.f) : 0.f;
                    HB[128 + r * 160 + n] = f2s(v);
                }
            }
        }
    }
    __syncthreads();   // B5: v1 visible

    // ---- head v2 + dot(w3): all waves, split the 7 n-tiles ----
    {
        bf16x8 a2h[5];
        #pragma unroll
        for (int kt = 0; kt < 5; ++kt)
            a2h[kt] = *(const bf16x8*)(HB + 128 + (c & 3) * 160 + kt * 32 + q * 8);
        float racc[4] = {0.f, 0.f, 0.f, 0.f};
        for (int nt = wv; nt < 7; nt += 4) {
            f32x4 d = z4;
            #pragma unroll
            for (int kt = 0; kt < 5; ++kt)
                d = MFMA16(a2h[kt], pk16[(68 + kt * 7 + nt) * 64 + lane], d);
            int n = nt * 16 + c;
            float bias = (n < 100) ? vn_b2[n] : 0.f;
            float w3   = (n < 100) ? vn_w3[n] : 0.f;
            #pragma unroll
            for (int r = 0; r < 4; ++r) racc[r] += fmaxf(d[r] + bias, 0.f) * w3;
        }
        #pragma unroll
        for (int m = 1; m <= 8; m <<= 1) {
            #pragma unroll
            for (int r = 0; r < 4; ++r) racc[r] += __shfl_xor(racc[r], m);
        }
        if (lane == 0) {
            float* P = (float*)(HB + 768);
            #pragma unroll
            for (int r = 0; r < 4; ++r) P[wv * 4 + r] = racc[r];
        }
    }
    __syncthreads();   // B6: partials visible

    if (tid < 4) {
        const float* P = (const float*)(HB + 768);
        out[blockIdx.x * 4 + tid] =
            P[tid] + P[4 + tid] + P[8 + tid] + P[12 + tid] + vn_b3[0];
    }
}

// ---------------------------------------------------------------------------
extern "C" void kernel_launch(void* const* d_in, const int* in_sizes, int n_in,
                              void* d_out, int out_size, void* d_ws, size_t ws_size,
                              hipStream_t stream) {
    const float* state    = (const float*)d_in[0];
    const float* wr_w1    = (const float*)d_in[2];
    const float* wr_b1    = (const float*)d_in[3];
    const float* wr_w2    = (const float*)d_in[4];
    const float* wr_b2    = (const float*)d_in[5];
    const float* wh_w1    = (const float*)d_in[6];
    const float* wh_b1    = (const float*)d_in[7];
    const float* wh_w2    = (const float*)d_in[8];
    const float* wh_b2    = (const float*)d_in[9];
    const float* rel_rh1  = (const float*)d_in[10];
    const float* brel_rh1 = (const float*)d_in[11];
    const float* root_rh1 = (const float*)d_in[12];
    const float* rel_hr1  = (const float*)d_in[13];
    const float* brel_hr1 = (const float*)d_in[14];
    const float* root_hr1 = (const float*)d_in[15];
    const float* rel_hh1  = (const float*)d_in[16];
    const float* brel_hh1 = (const float*)d_in[17];
    const float* root_hh1 = (const float*)d_in[18];
    // 19..21, 25..27 dead (layer-2 new_h unused)
    const float* rel_hr2  = (const float*)d_in[22];
    const float* brel_hr2 = (const float*)d_in[23];
    const float* root_hr2 = (const float*)d_in[24];
    const float* vn_w1    = (const float*)d_in[28];
    const float* vn_b1    = (const float*)d_in[29];
    const float* vn_w2    = (const float*)d_in[30];
    const float* vn_b2    = (const float*)d_in[31];
    const float* vn_w3    = (const float*)d_in[32];
    const float* vn_b3    = (const float*)d_in[33];
    float* out = (float*)d_out;
    short* pk  = (short*)d_ws;               // needs ~106 KB of workspace

    pack_frags<<<207, 256, 0, stream>>>(wh_w1, wh_b1, wh_w2,
                                        root_rh1, root_hh1, rel_hh1, wr_w2,
                                        rel_hr1, root_hr1, rel_rh1,
                                        rel_hr2, root_hr2, vn_w1, vn_w2,
                                        brel_hr1, brel_rh1, brel_hh1, brel_hr2, pk);
    fused_main<<<BTOT / 4, 256, 0, stream>>>(state, pk, wr_w1, wr_b1, wr_b2, wh_b2,
                                             vn_b1, vn_b2, vn_w3, vn_b3, out);
}

// Round 10
// 182.517 us; speedup vs baseline: 1.0979x; 1.0689x over previous
//
#include <hip/hip_runtime.h>

#define BTOT 16384

typedef __attribute__((ext_vector_type(8))) short bf16x8;   // 8 bf16 in 4 VGPRs
typedef __attribute__((ext_vector_type(4))) float f32x4;

#define MFMA16(a,b,c) __builtin_amdgcn_mfma_f32_16x16x32_bf16((a),(b),(c),0,0,0)

// ---- bf16 conversion helpers: HW packed cvt if available, manual RNE else ----
#if __has_builtin(__builtin_amdgcn_cvt_pk_bf16_f32)
typedef __attribute__((ext_vector_type(2))) __bf16 hwbf2;
static __device__ __forceinline__ unsigned pk2(float a, float b) {
    hwbf2 v = __builtin_amdgcn_cvt_pk_bf16_f32(a, b);
    return __builtin_bit_cast(unsigned, v);
}
#else
static __device__ __forceinline__ unsigned pk2(float a, float b) {
    unsigned ua = __float_as_uint(a), ub = __float_as_uint(b);
    unsigned ra = (ua + 0x7FFFu + ((ua >> 16) & 1u)) >> 16;
    unsigned rb = (ub + 0x7FFFu + ((ub >> 16) & 1u)) >> 16;
    return (ra & 0xFFFFu) | (rb << 16);
}
#endif
static __device__ __forceinline__ unsigned short bfhi(float x) {
    return (unsigned short)(pk2(x, 0.f) & 0xFFFFu);
}
static __device__ __forceinline__ float b2f(unsigned short h) {
    return __uint_as_float(((unsigned)h) << 16);
}
static __device__ __forceinline__ short f2s(float x) { return (short)bfhi(x); }
// manual RNE for the pack kernel (identical rounding either path)
static __device__ __forceinline__ unsigned short bfhi_m(float x) {
    unsigned u = __float_as_uint(x);
    return (unsigned short)((u + 0x7FFFu + ((u >> 16) & 1u)) >> 16);
}
static __device__ __forceinline__ unsigned short bflo_m(float x) {
    unsigned short h = bfhi_m(x);
    return bfhi_m(x - b2f(h));
}
static __device__ __forceinline__ bf16x8 zero8() {
    bf16x8 v;
    #pragma unroll
    for (int i = 0; i < 8; ++i) v[i] = 0;
    return v;
}

// ---------------------------------------------------------------------------
// Workspace (shorts). Frags are 512 shorts each, frag f at pk[f*512 + lane*8 + j].
// f 0..3 A1 | 4..7 Bh2 (K-order matched to paired-b128 t storage) |
// 8..9 Be (K-permuted: k_old=(k>>1)+((k&1)<<4)) | 10..21 BrL2(split K=192) |
// 22..45 Bg1(split) | 46..57 Bg2(split) | 58..67 Bv1 | 68..102 Bv2.
// shorts 52736..52864: bg1 f32[64]; 52864..52928: bg2 f32[32];
// 53248..+524288: r2 bf16. Total ~1.16 MB.
// ---------------------------------------------------------------------------
__global__ void pack_frags(
    const float* __restrict__ wh_w1, const float* __restrict__ wh_b1,
    const float* __restrict__ wh_w2,
    const float* __restrict__ root_rh1, const float* __restrict__ root_hh1,
    const float* __restrict__ rel_hh1,
    const float* __restrict__ wr_w2,
    const float* __restrict__ rel_hr1, const float* __restrict__ root_hr1,
    const float* __restrict__ rel_rh1,
    const float* __restrict__ rel_hr2, const float* __restrict__ root_hr2,
    const float* __restrict__ vn_w1, const float* __restrict__ vn_w2,
    const float* __restrict__ brel_hr1, const float* __restrict__ brel_rh1,
    const float* __restrict__ brel_hh1, const float* __restrict__ brel_hr2,
    short* __restrict__ pk)
{
    int t = blockIdx.x * blockDim.x + threadIdx.x;
    if (t < 52736) {
        int f = t >> 9, r = t & 511;
        int lane = r >> 3, j = r & 7;
        int q = lane >> 4, c = lane & 15;
        int k = q * 8 + j;
        unsigned short outv;
        if (f < 4) {                                   // A1: Wh1^T (+bias row k=7)
            int m = f * 16 + c;
            float v = (k < 7) ? wh_w1[k * 64 + m] : (k == 7 ? wh_b1[m] : 0.f);
            outv = bfhi_m(v);
        } else if (f < 8) {                            // Bh2; K-order for paired t
            int u = f - 4, ks = u >> 1, nt = u & 1;
            int kr = ks * 32 + (j >> 2) * 16 + q * 4 + (j & 3);
            outv = bfhi_m(wh_w2[kr * 32 + nt * 16 + c]);
        } else if (f < 10) {                           // Be (W1eff), K-permuted for
            int n = (f - 8) * 16 + c;                  // interleaved h layout
            int ko = (k >> 1) + ((k & 1) << 4);
            outv = bfhi_m(root_rh1[ko * 32 + n] + root_hh1[ko * 32 + n] - rel_hh1[ko * 32 + n]);
        } else if (f < 22) {                           // BrL2 split
            int u = f - 10, ks = u >> 1, nt = u & 1;
            int kp = ks * 32 + k;                      // 0..191
            float w = wr_w2[(kp & 63) * 32 + nt * 16 + c];
            outv = (kp < 128) ? bfhi_m(w) : bflo_m(w);
        } else if (f < 46) {                           // Bg1 split
            int u = f - 22, ks = u >> 2, nt = u & 3;
            int kp = ks * 32 + k, seg = kp >> 5, kk = kp & 31;
            int n2 = (nt & 1) * 16 + c;
            bool sPart = (seg < 2) || (seg == 4);
            const float* W = (nt < 2) ? (sPart ? rel_hr1 : root_hr1)
                                      : (sPart ? rel_hh1 : rel_rh1);
            float w = W[kk * 32 + n2];
            outv = (seg < 4) ? bfhi_m(w) : bflo_m(w);
        } else if (f < 58) {                           // Bg2 split
            int u = f - 46, ks = u >> 1, nt = u & 1;
            int kp = ks * 32 + k, seg = kp >> 5, kk = kp & 31;
            int n = nt * 16 + c;
            bool sPart = (seg < 2) || (seg == 4);
            const float* W = sPart ? rel_hr2 : root_hr2;
            float w = W[kk * 32 + n];
            outv = (seg < 4) ? bfhi_m(w) : bflo_m(w);
        } else if (f < 68) {                           // Bv1
            int n = (f - 58) * 16 + c;
            outv = (n < 150) ? bfhi_m(vn_w1[k * 150 + n]) : 0;
        } else {                                       // Bv2
            int u = f - 68, kt = u / 7, nt = u - kt * 7;
            int kk = kt * 32 + k, n = nt * 16 + c;
            outv = (kk < 150 && n < 100) ? bfhi_m(vn_w2[kk * 100 + n]) : 0;
        }
        pk[t] = (short)outv;
    } else if (t < 52800) {
        int i = t - 52736;
        float* bp = (float*)(pk + 52736);
        bp[i] = (i < 32) ? brel_hr1[i] : brel_rh1[i - 32] + brel_hh1[i - 32];
    } else if (t < 52832) {
        int i = t - 52800;
        float* bp = (float*)(pk + 52864);
        bp[i] = brel_hr2[i];
    }
}

// ---------------------------------------------------------------------------
// Main fused kernel: wave = one batch row; per-wave T[4096 shorts] (8 KB).
// t: rows 0..63 at row*64 shorts, 8 b128 units/row, unit p = (mhp*4+q)^(c&7).
// h: rows 0..63 at row*32, cols interleaved, unit swizzle ^(row&3).
// Tail overlays (written only after the t rows they alias are consumed):
// c1 f32 @3456, g2in @3520, sbuf @3712, trh @3904.
// ---------------------------------------------------------------------------
__global__ __launch_bounds__(256) void fused_main(
    const float* __restrict__ state, const short* __restrict__ pk,
    const float* __restrict__ wr_w1, const float* __restrict__ wr_b1,
    const float* __restrict__ wr_b2, const float* __restrict__ wh_b2,
    short* __restrict__ r2buf)
{
    __shared__ __align__(16) short wbuf[4][4096];

    const int tid = threadIdx.x;
    const int wv = tid >> 6, lane = tid & 63;
    const int q = lane >> 4, c = lane & 15;
    const int b = blockIdx.x * 4 + wv;
    const float* st = state + (size_t)b * 832;
    short* T = wbuf[wv];

    const bf16x8* pk16 = (const bf16x8*)pk;
    const float* bg1f = (const float*)(pk + 52736);
    const float* bg2f = (const float*)(pk + 52864);
    const f32x4 z4 = {0.f, 0.f, 0.f, 0.f};

    bf16x8 A1[4], Bh2v[4], Bev[2];
    #pragma unroll
    for (int i = 0; i < 4; ++i) A1[i] = pk16[i * 64 + lane];
    #pragma unroll
    for (int i = 0; i < 4; ++i) Bh2v[i] = pk16[(4 + i) * 64 + lane];
    #pragma unroll
    for (int i = 0; i < 2; ++i) Bev[i] = pk16[(8 + i) * 64 + lane];

    {   // own human's features -> LDS, B-ready (k=0..6 feats, k=7 -> 1.0)
        float hf[7];
        #pragma unroll
        for (int m = 0; m < 7; ++m) hf[m] = st[lane * 13 + 6 + m];
        uint4 v = make_uint4(pk2(hf[0], hf[1]), pk2(hf[2], hf[3]),
                             pk2(hf[4], hf[5]), pk2(hf[6], 1.0f));
        *(uint4*)(T + lane * 8) = v;
    }

    float trh;   // r-MLP hidden (lane = hidden unit)
    {
        float acc = wr_b1[lane];
        #pragma unroll
        for (int m = 0; m < 6; ++m) acc = fmaf(st[m], wr_w1[m * 64 + lane], acc);
        trh = fmaxf(acc, 0.f);
    }

    asm volatile("s_waitcnt lgkmcnt(0)" ::: "memory");

    bf16x8 bx[4];
    #pragma unroll
    for (int ht = 0; ht < 4; ++ht) {
        bf16x8 v = zero8();
        if (q == 0) v = *(const bf16x8*)(T + (ht * 16 + c) * 8);
        bx[ht] = v;
    }

    // S1': t^T = Wh1^T @ x^T; paired mh tiles -> one b128 write per (mhp,ht)
    #pragma unroll
    for (int mhp = 0; mhp < 2; ++mhp) {
        #pragma unroll
        for (int ht = 0; ht < 4; ++ht) {
            f32x4 d0 = MFMA16(A1[2 * mhp + 0], bx[ht], z4);
            f32x4 d1 = MFMA16(A1[2 * mhp + 1], bx[ht], z4);
            d0 = __builtin_elementwise_max(d0, z4);
            d1 = __builtin_elementwise_max(d1, z4);
            uint4 w = make_uint4(pk2(d0[0], d0[1]), pk2(d0[2], d0[3]),
                                 pk2(d1[0], d1[1]), pk2(d1[2], d1[3]));
            int row = ht * 16 + c;
            int p = (mhp * 4 + q) ^ (c & 7);
            *(uint4*)(T + row * 64 + p * 8) = w;
        }
    }

    asm volatile("s_waitcnt lgkmcnt(0)" ::: "memory");

    // S2: h = t @ Wh2 (+b2, relu); packed-pair h rows + vector s-accumulators
    const float b2a = wh_b2[c], b2b = wh_b2[16 + c];
    const f32x4 b2a4 = {b2a, b2a, b2a, b2a}, b2b4 = {b2b, b2b, b2b, b2b};
    f32x4 psv0 = z4, psv1 = z4;
    #pragma unroll
    for (int mt = 0; mt < 4; ++mt) {
        int row = mt * 16 + c;
        bf16x8 a0 = *(const bf16x8*)(T + row * 64 + ((q ^ (c & 7))) * 8);
        bf16x8 a1 = *(const bf16x8*)(T + row * 64 + (((q + 4) ^ (c & 7))) * 8);
        f32x4 e0 = MFMA16(a0, Bh2v[0], z4); e0 = MFMA16(a1, Bh2v[2], e0);
        f32x4 e1 = MFMA16(a0, Bh2v[1], z4); e1 = MFMA16(a1, Bh2v[3], e1);
        e0 = __builtin_elementwise_max(e0 + b2a4, z4);
        e1 = __builtin_elementwise_max(e1 + b2b4, z4);
        psv0 += e0; psv1 += e1;
        #pragma unroll
        for (int r = 0; r < 4; ++r) {
            int hrow = mt * 16 + q * 4 + r;
            *(unsigned*)(T + hrow * 32 + (((c >> 2) ^ r)) * 8 + (c & 3) * 2) = pk2(e0[r], e1[r]);
        }
    }
    float ps0 = (psv0[0] + psv0[1]) + (psv0[2] + psv0[3]);
    float ps1 = (psv1[0] + psv1[1]) + (psv1[2] + psv1[3]);
    ps0 += __shfl_xor(ps0, 16); ps0 += __shfl_xor(ps0, 32);
    ps1 += __shfl_xor(ps1, 16); ps1 += __shfl_xor(ps1, 32);

    {   // s -> sbuf: [s_hi;s_lo;r_hi;r_lo;s_hi;r_hi], trh -> [hi;lo;hi]
        short* SB = T + 3712;
        if (q == 0) {
            unsigned short h0 = bfhi(ps0), h1 = bfhi(ps1);
            SB[c] = (short)h0;        SB[16 + c] = (short)h1;
            SB[32 + c] = (short)bfhi(ps0 - b2f(h0));
            SB[48 + c] = (short)bfhi(ps1 - b2f(h1));
            SB[128 + c] = (short)h0;  SB[144 + c] = (short)h1;
        }
        short* TR = T + 3904;
        unsigned short th = bfhi(trh);
        TR[lane] = (short)th;
        TR[64 + lane] = (short)bfhi(trh - b2f(th));
        TR[128 + lane] = (short)th;
    }
    __syncthreads();   // B1

    if (wv == 0) {     // rL2 + glue1 for the block's 4 rows (split-bf16 K=192)
        bf16x8 art[6];
        #pragma unroll
        for (int ks = 0; ks < 6; ++ks) {
            bf16x8 v = zero8();
            if (c < 4) v = *(const bf16x8*)(wbuf[c] + 3904 + ks * 32 + q * 8);
            art[ks] = v;
        }
        f32x4 dr0 = z4, dr1 = z4;
        #pragma unroll
        for (int ks = 0; ks < 6; ++ks) {
            dr0 = MFMA16(art[ks], pk16[(10 + ks * 2 + 0) * 64 + lane], dr0);
            dr1 = MFMA16(art[ks], pk16[(10 + ks * 2 + 1) * 64 + lane], dr1);
        }
        const float wb0 = wr_b2[c], wb1 = wr_b2[16 + c];
        if (q == 0) {
            #pragma unroll
            for (int r = 0; r < 4; ++r) {
                float v0 = fmaxf(dr0[r] + wb0, 0.f), v1 = fmaxf(dr1[r] + wb1, 0.f);
                short* SBr = wbuf[r] + 3712;
                unsigned short h0 = bfhi(v0), h1 = bfhi(v1);
                SBr[64 + c] = (short)h0;  SBr[96 + c]  = (short)bfhi(v0 - b2f(h0));  SBr[160 + c] = (short)h0;
                SBr[80 + c] = (short)h1;  SBr[112 + c] = (short)bfhi(v1 - b2f(h1));  SBr[176 + c] = (short)h1;
            }
        }
        asm volatile("s_waitcnt lgkmcnt(0)" ::: "memory");

        bf16x8 ag[6];
        #pragma unroll
        for (int ks = 0; ks < 6; ++ks) {
            bf16x8 v = zero8();
            if (c < 4) v = *(const bf16x8*)(wbuf[c] + 3712 + ks * 32 + q * 8);
            ag[ks] = v;
        }
        f32x4 dg[4] = {z4, z4, z4, z4};
        #pragma unroll
        for (int ks = 0; ks < 6; ++ks) {
            #pragma unroll
            for (int nt = 0; nt < 4; ++nt)
                dg[nt] = MFMA16(ag[ks], pk16[(22 + ks * 4 + nt) * 64 + lane], dg[nt]);
        }
        if (q == 0) {
            #pragma unroll
            for (int nt = 0; nt < 2; ++nt) {
                float bias = bg1f[nt * 16 + c];
                #pragma unroll
                for (int r = 0; r < 4; ++r) {       // r1 -> g2in
                    float v = fmaxf(dg[nt][r] + bias, 0.f);
                    short* G2r = wbuf[r] + 3520;
                    unsigned short hh = bfhi(v);
                    G2r[64 + nt * 16 + c]  = (short)hh;
                    G2r[96 + nt * 16 + c]  = (short)bfhi(v - b2f(hh));
                    G2r[160 + nt * 16 + c] = (short)hh;
                }
            }
            #pragma unroll
            for (int nt = 2; nt < 4; ++nt) {
                float bias = bg1f[nt * 16 + c];
                #pragma unroll
                for (int r = 0; r < 4; ++r)         // c1 (f32, no relu)
                    ((float*)(wbuf[r] + 3456))[(nt - 2) * 16 + c] = dg[nt][r] + bias;
            }
        }
    }
    __syncthreads();   // B2

    {   // S4: s2 = sum_hu relu(c1 + h @ W1eff)   (h interleaved, Be K-permuted)
        const float* C1 = (const float*)(T + 3456);
        const float c10 = C1[c], c11 = C1[16 + c];
        const f32x4 c10v = {c10, c10, c10, c10}, c11v = {c11, c11, c11, c11};
        f32x4 acc0 = z4, acc1 = z4;
        #pragma unroll
        for (int mt = 0; mt < 4; ++mt) {
            int row = mt * 16 + c;
            bf16x8 ah = *(const bf16x8*)(T + row * 32 + ((q ^ (c & 3))) * 8);
            f32x4 g0 = MFMA16(ah, Bev[0], z4);
            f32x4 g1 = MFMA16(ah, Bev[1], z4);
            acc0 += __builtin_elementwise_max(g0 + c10v, z4);
            acc1 += __builtin_elementwise_max(g1 + c11v, z4);
        }
        float t0 = (acc0[0] + acc0[1]) + (acc0[2] + acc0[3]);
        float t1 = (acc1[0] + acc1[1]) + (acc1[2] + acc1[3]);
        t0 += __shfl_xor(t0, 16); t0 += __shfl_xor(t0, 32);
        t1 += __shfl_xor(t1, 16); t1 += __shfl_xor(t1, 32);
        short* G2 = T + 3520;   // [s2_hi(32); s2_lo(32); r1...; s2_hi(32); r1...]
        if (q == 0) {
            unsigned short h0 = bfhi(t0), h1 = bfhi(t1);
            G2[c] = (short)h0;        G2[16 + c] = (short)h1;
            G2[32 + c] = (short)bfhi(t0 - b2f(h0));
            G2[48 + c] = (short)bfhi(t1 - b2f(h1));
            G2[128 + c] = (short)h0;  G2[144 + c] = (short)h1;
        }
    }
    __syncthreads();   // B3

    if (wv == 0) {     // glue2 -> r2
        bf16x8 a2[6];
        #pragma unroll
        for (int ks = 0; ks < 6; ++ks) {
            bf16x8 v = zero8();
            if (c < 4) v = *(const bf16x8*)(wbuf[c] + 3520 + ks * 32 + q * 8);
            a2[ks] = v;
        }
        f32x4 d0 = z4, d1 = z4;
        #pragma unroll
        for (int ks = 0; ks < 6; ++ks) {
            d0 = MFMA16(a2[ks], pk16[(46 + ks * 2 + 0) * 64 + lane], d0);
            d1 = MFMA16(a2[ks], pk16[(46 + ks * 2 + 1) * 64 + lane], d1);
        }
        if (q == 0) {
            const int b0 = blockIdx.x * 4;
            const float g0 = bg2f[c], g1 = bg2f[16 + c];
            #pragma unroll
            for (int r = 0; r < 4; ++r) {
                r2buf[(b0 + r) * 32 + c]      = f2s(fmaxf(d0[r] + g0, 0.f));
                r2buf[(b0 + r) * 32 + 16 + c] = f2s(fmaxf(d1[r] + g1, 0.f));
            }
        }
    }
}

// ---------------------------------------------------------------------------
__global__ __launch_bounds__(256) void head_kernel(
    const short* __restrict__ pk,
    const float* __restrict__ vn_b1, const float* __restrict__ vn_b2,
    const float* __restrict__ vn_w3, const float* __restrict__ vn_b3,
    float* __restrict__ out)
{
    __shared__ __align__(16) short sh_v1[4][16 * 168];
    const int wv = threadIdx.x >> 6, lane = threadIdx.x & 63;
    const int q = lane >> 4, c = lane & 15;
    const int tile = blockIdx.x * 4 + wv;
    const bf16x8* wf = (const bf16x8*)pk;
    const short* r2b = pk + 53248;
    const f32x4 z4 = {0.f, 0.f, 0.f, 0.f};

    bf16x8 a1 = *(const bf16x8*)&r2b[(tile * 16 + c) * 32 + q * 8];
    short* vb = sh_v1[wv];
    #pragma unroll
    for (int nt = 0; nt < 10; ++nt) {
        f32x4 d = MFMA16(a1, wf[(58 + nt) * 64 + lane], z4);
        int n = nt * 16 + c;
        float bias = (n < 150) ? vn_b1[n] : 0.f;
        #pragma unroll
        for (int r = 0; r < 4; ++r) {
            float v = (n < 150) ? fmaxf(d[r] + bias, 0.f) : 0.f;
            vb[(q * 4 + r) * 168 + n] = f2s(v);
        }
    }
    __syncthreads();

    bf16x8 a2[5];
    #pragma unroll
    for (int kt = 0; kt < 5; ++kt)
        a2[kt] = *(const bf16x8*)&vb[c * 168 + kt * 32 + q * 8];

    float racc[4] = {0.f, 0.f, 0.f, 0.f};
    #pragma unroll
    for (int nt = 0; nt < 7; ++nt) {
        f32x4 d = z4;
        #pragma unroll
        for (int kt = 0; kt < 5; ++kt)
            d = MFMA16(a2[kt], wf[(68 + kt * 7 + nt) * 64 + lane], d);
        int n = nt * 16 + c;
        float bias = (n < 100) ? vn_b2[n] : 0.f;
        float w3   = (n < 100) ? vn_w3[n] : 0.f;
        #pragma unroll
        for (int r = 0; r < 4; ++r) racc[r] += fmaxf(d[r] + bias, 0.f) * w3;
    }
    #pragma unroll
    for (int m = 1; m < 16; m <<= 1) {
        #pragma unroll
        for (int r = 0; r < 4; ++r) racc[r] += __shfl_xor(racc[r], m);
    }
    if (c == 0) {
        float b3 = vn_b3[0];
        #pragma unroll
        for (int r = 0; r < 4; ++r) out[tile * 16 + q * 4 + r] = racc[r] + b3;
    }
}

// ---------------------------------------------------------------------------
extern "C" void kernel_launch(void* const* d_in, const int* in_sizes, int n_in,
                              void* d_out, int out_size, void* d_ws, size_t ws_size,
                              hipStream_t stream) {
    const float* state    = (const float*)d_in[0];
    const float* wr_w1    = (const float*)d_in[2];
    const float* wr_b1    = (const float*)d_in[3];
    const float* wr_w2    = (const float*)d_in[4];
    const float* wr_b2    = (const float*)d_in[5];
    const float* wh_w1    = (const float*)d_in[6];
    const float* wh_b1    = (const float*)d_in[7];
    const float* wh_w2    = (const float*)d_in[8];
    const float* wh_b2    = (const float*)d_in[9];
    const float* rel_rh1  = (const float*)d_in[10];
    const float* brel_rh1 = (const float*)d_in[11];
    const float* root_rh1 = (const float*)d_in[12];
    const float* rel_hr1  = (const float*)d_in[13];
    const float* brel_hr1 = (const float*)d_in[14];
    const float* root_hr1 = (const float*)d_in[15];
    const float* rel_hh1  = (const float*)d_in[16];
    const float* brel_hh1 = (const float*)d_in[17];
    const float* root_hh1 = (const float*)d_in[18];
    // 19..21, 25..27 dead (layer-2 new_h unused)
    const float* rel_hr2  = (const float*)d_in[22];
    const float* brel_hr2 = (const float*)d_in[23];
    const float* root_hr2 = (const float*)d_in[24];
    const float* vn_w1    = (const float*)d_in[28];
    const float* vn_b1    = (const float*)d_in[29];
    const float* vn_w2    = (const float*)d_in[30];
    const float* vn_b2    = (const float*)d_in[31];
    const float* vn_w3    = (const float*)d_in[32];
    const float* vn_b3    = (const float*)d_in[33];
    float* out = (float*)d_out;
    short* pk  = (short*)d_ws;               // needs ~1.16 MB of workspace
    short* r2buf = pk + 53248;

    pack_frags<<<207, 256, 0, stream>>>(wh_w1, wh_b1, wh_w2,
                                        root_rh1, root_hh1, rel_hh1, wr_w2,
                                        rel_hr1, root_hr1, rel_rh1,
                                        rel_hr2, root_hr2, vn_w1, vn_w2,
                                        brel_hr1, brel_rh1, brel_hh1, brel_hr2, pk);
    fused_main<<<BTOT / 4, 256, 0, stream>>>(state, pk, wr_w1, wr_b1, wr_b2, wh_b2, r2buf);
    head_kernel<<<BTOT / 64, 256, 0, stream>>>(pk, vn_b1, vn_b2, vn_w3, vn_b3, out);
}